// Round 1
// baseline (645.923 us; speedup 1.0000x reference)
//
#include <hip/hip_runtime.h>

// EmbeddingBagList: T=26 tables, V=1000 rows, D=128 dims, B=8192 bags, NNZ=409600 idx/table.
// One wave per bag. Lanes split into two half-waves of 32; each half-wave handles one
// index (row) at a time, 32 lanes x float4 = the full 512B row, perfectly coalesced.
// Halves combine via shfl at the end. XCD swizzle: blockIdx%8 selects which tables
// (t = xcd + 8*slot) so each XCD's 4MB L2 only caches ~3-4 tables (<=2MB) of weights.

#define T_ 26
#define V_ 1000
#define D_ 128
#define B_ 8192
#define NNZ_ 409600

__global__ __launch_bounds__(256) void embag_kernel(
    const float* __restrict__ weights,   // [T, V, D]
    const int*   __restrict__ indices,   // [T, NNZ]
    const int*   __restrict__ offsets,   // [T, B] sorted, offsets[:,0]==0
    float*       __restrict__ out)       // [T, B, D]
{
    const int bid   = blockIdx.x;
    const int xcd   = bid & 7;        // heuristic: dispatch round-robins blocks over 8 XCDs
    const int r     = bid >> 3;       // 0..8191
    const int tslot = r & 3;          // 0..3
    const int chunk = r >> 2;         // 0..2047
    const int t     = xcd + 8 * tslot;
    if (t >= T_) return;              // 26 tables over 8x4 slots: some slots empty

    const int wave = threadIdx.x >> 6;  // 4 waves per block, one bag each
    const int lane = threadIdx.x & 63;
    const int bag  = chunk * 4 + wave;  // 0..8191

    const int* off = offsets + t * B_;
    const int start = off[bag];
    const int end   = (bag == B_ - 1) ? NNZ_ : off[bag + 1];

    const float* wt  = weights + (size_t)t * V_ * D_;
    const int*   ind = indices + (size_t)t * NNZ_;

    const int half = lane >> 5;   // which index of the pair this lane works on
    const int dl   = lane & 31;   // dim group: floats [4*dl, 4*dl+4)

    float4 acc = make_float4(0.f, 0.f, 0.f, 0.f);
    for (int i = start + half; i < end; i += 2) {
        const int idx = ind[i];
        const float4 row = *(const float4*)(wt + (size_t)idx * D_ + dl * 4);
        acc.x += row.x; acc.y += row.y; acc.z += row.z; acc.w += row.w;
    }

    // combine the two half-wave partials (lane i += lane i+32)
    acc.x += __shfl_down(acc.x, 32, 64);
    acc.y += __shfl_down(acc.y, 32, 64);
    acc.z += __shfl_down(acc.z, 32, 64);
    acc.w += __shfl_down(acc.w, 32, 64);

    if (half == 0) {
        *(float4*)(out + ((size_t)t * B_ + bag) * D_ + dl * 4) = acc;
    }
}

extern "C" void kernel_launch(void* const* d_in, const int* in_sizes, int n_in,
                              void* d_out, int out_size, void* d_ws, size_t ws_size,
                              hipStream_t stream) {
    const float* weights = (const float*)d_in[0];
    const int*   indices = (const int*)d_in[1];
    const int*   offsets = (const int*)d_in[2];
    float*       out     = (float*)d_out;

    // 8 xcd slots x 4 table slots x 2048 bag-chunks (4 bags each) = 65536 blocks
    const int num_blocks = 8 * 4 * (B_ / 4);
    embag_kernel<<<num_blocks, 256, 0, stream>>>(weights, indices, offsets, out);
}

// Round 3
// 403.110 us; speedup vs baseline: 1.6024x; 1.6024x over previous
//
#include <hip/hip_runtime.h>

// EmbeddingBagList: T=26 tables, V=1000 rows, D=128 dims, B=8192 bags, NNZ=409600 idx/table.
// One wave per bag; two half-waves of 32 lanes; 32 lanes x float4 = full 512B row.
// Round-2 failed: divergent __shfl read from inactive cross-half lanes (ds_bpermute
// gives invalid data for EXEC=0 source lanes). Round-3 fix: remap the batched index
// load so half h's shfl sources are always lanes [32h, 32h+31] (own half, always
// active when that half executes). Lane l holds row ((l&31)*2 + (l>>5)).
// ILP: 4 independent row loads in flight per half-wave, dual accumulators.
// XCD swizzle keeps each XCD's 3-4 tables (<=2MB) resident in its 4MB L2
// (confirmed round 1: FETCH_SIZE ~27MB, WRITE_SIZE == ideal 106MB).

#define T_ 26
#define V_ 1000
#define D_ 128
#define B_ 8192
#define NNZ_ 409600

__global__ __launch_bounds__(256) void embag_kernel(
    const float* __restrict__ weights,   // [T, V, D]
    const int*   __restrict__ indices,   // [T, NNZ]
    const int*   __restrict__ offsets,   // [T, B] sorted, offsets[:,0]==0
    float*       __restrict__ out)       // [T, B, D]
{
    const int bid   = blockIdx.x;
    const int xcd   = bid & 7;        // dispatch round-robins blocks over 8 XCDs
    const int r     = bid >> 3;
    const int tslot = r & 3;
    const int chunk = r >> 2;
    const int t     = xcd + 8 * tslot;
    if (t >= T_) return;

    const int wave = threadIdx.x >> 6;  // 4 waves per block, one bag each
    const int lane = threadIdx.x & 63;
    const int bag  = chunk * 4 + wave;

    const int* off = offsets + t * B_;
    const int start = off[bag];
    const int end   = (bag == B_ - 1) ? NNZ_ : off[bag + 1];

    const float* wt  = weights + (size_t)t * V_ * D_;
    const int*   ind = indices + (size_t)t * NNZ_;

    const int half  = lane >> 5;   // which parity of rows this half-wave sums
    const int dl    = lane & 31;   // dim group: floats [4*dl, 4*dl+4)
    const int col   = dl * 4;
    const int lbase = half << 5;   // shfl source base: own half only

    float4 acc0 = make_float4(0.f, 0.f, 0.f, 0.f);
    float4 acc1 = make_float4(0.f, 0.f, 0.f, 0.f);

    for (int base = start; base < end; base += 64) {
        const int cnt = (end - base < 64) ? (end - base) : 64;

        // lane l caches row (2*(l&31) + (l>>5)); half h's rows live in lanes [32h,32h+31]
        const int rowload = (dl << 1) + half;
        int myidx = 0;
        if (rowload < cnt) myidx = ind[base + rowload];

        // this half sums rows 2k+half, k=0..nk-1; source lane = lbase + k (always own half)
        const int nk = (cnt - half + 1) >> 1;
        int k = 0;
        for (; k + 3 < nk; k += 4) {
            const int i0 = __shfl(myidx, lbase + k);
            const int i1 = __shfl(myidx, lbase + k + 1);
            const int i2 = __shfl(myidx, lbase + k + 2);
            const int i3 = __shfl(myidx, lbase + k + 3);
            const float4 r0 = *(const float4*)(wt + (size_t)i0 * D_ + col);
            const float4 r1 = *(const float4*)(wt + (size_t)i1 * D_ + col);
            const float4 r2 = *(const float4*)(wt + (size_t)i2 * D_ + col);
            const float4 r3 = *(const float4*)(wt + (size_t)i3 * D_ + col);
            acc0.x += r0.x; acc0.y += r0.y; acc0.z += r0.z; acc0.w += r0.w;
            acc1.x += r1.x; acc1.y += r1.y; acc1.z += r1.z; acc1.w += r1.w;
            acc0.x += r2.x; acc0.y += r2.y; acc0.z += r2.z; acc0.w += r2.w;
            acc1.x += r3.x; acc1.y += r3.y; acc1.z += r3.z; acc1.w += r3.w;
        }
        for (; k < nk; ++k) {
            const int i0 = __shfl(myidx, lbase + k);
            const float4 r0 = *(const float4*)(wt + (size_t)i0 * D_ + col);
            acc0.x += r0.x; acc0.y += r0.y; acc0.z += r0.z; acc0.w += r0.w;
        }
    }

    float4 acc;
    acc.x = acc0.x + acc1.x;
    acc.y = acc0.y + acc1.y;
    acc.z = acc0.z + acc1.z;
    acc.w = acc0.w + acc1.w;

    // combine the two half-wave partials (lane i += lane i+32); wave fully convergent here
    acc.x += __shfl_down(acc.x, 32, 64);
    acc.y += __shfl_down(acc.y, 32, 64);
    acc.z += __shfl_down(acc.z, 32, 64);
    acc.w += __shfl_down(acc.w, 32, 64);

    if (half == 0) {
        *(float4*)(out + ((size_t)t * B_ + bag) * D_ + col) = acc;
    }
}

extern "C" void kernel_launch(void* const* d_in, const int* in_sizes, int n_in,
                              void* d_out, int out_size, void* d_ws, size_t ws_size,
                              hipStream_t stream) {
    const float* weights = (const float*)d_in[0];
    const int*   indices = (const int*)d_in[1];
    const int*   offsets = (const int*)d_in[2];
    float*       out     = (float*)d_out;

    // 8 xcd slots x 4 table slots x 2048 bag-chunks (4 bags each) = 65536 blocks
    const int num_blocks = 8 * 4 * (B_ / 4);
    embag_kernel<<<num_blocks, 256, 0, stream>>>(weights, indices, offsets, out);
}